// Round 14
// baseline (204.168 us; speedup 1.0000x reference)
//
#include <hip/hip_runtime.h>
#include <math.h>

#define NB 10
#define H 512
#define W 512
#define HW (H * W)
#define OH 507
#define OW 507
#define TW 32           // output tile width
#define TH 16           // output tile height
#define HC 39           // hist cols
#define HR 23           // hist rows
#define IC 41           // xin cols
#define IR 25           // xin rows
#define BD 512          // 8 waves/block, 4 blocks/CU -> 32 waves/CU
#define ZI 4            // images per block
#define HSTRIDE (HR * HC)        // 897
#define HISTF (NB * HSTRIDE + 2) // 8972 (pad -> clean float4 zero)
#define XINF (IR * IC)           // 1025

// numpy float32 remainder (np.mod): fmod then sign-fix, each op exact IEEE f32.
__device__ __forceinline__ float f32mod10(float a) {
    float r = fmodf(a, 10.0f);
    if (r < 0.0f) r = __fadd_rn(r, 10.0f);
    return r;
}

__global__ __launch_bounds__(BD, 8)
void hog_fused(const float* __restrict__ x, float* __restrict__ out) {
    __shared__ __align__(16) float hist[HISTF];   // 8972 f
    __shared__ __align__(16) float xin[XINF];     // 1025 f  -> 39,988 B total

    const int tid = threadIdx.x;
    const int ox0 = blockIdx.x * TW;
    const int oy0 = blockIdx.y * TH;
    const int n0  = blockIdx.z * ZI;

    // ---- per-thread input-cell descriptors (cells tid, tid+512, [tid0: 1024]) ----
    const int i1 = tid, i2 = tid + BD;
    int r1 = i1 / IC, c1 = i1 - r1 * IC;
    int r2 = i2 / IC, c2 = i2 - r2 * IC;
    int gy1 = oy0 - 2 + r1, gx1 = ox0 - 2 + c1;
    int gy2 = oy0 - 2 + r2, gx2 = ox0 - 2 + c2;
    const bool v1 = (unsigned)gy1 < H && (unsigned)gx1 < W;
    const bool v2 = (unsigned)gy2 < H && (unsigned)gx2 < W;
    const int off1 = gy1 * W + gx1, off2 = gy2 * W + gx2;
    const bool v3 = (tid == 0) && ((unsigned)(oy0 + 22) < H) && ((unsigned)(ox0 + 38) < W);
    const int off3 = (oy0 + 22) * W + (ox0 + 38);

    // ---- prime: reg-staged load of image n0's tile (T14; no global_load_lds:
    //      its LDS base is readfirstlane-uniform -> shifts when lane 0 masked) ----
    float pv1, pv2, pv3;
    {
        const float* xb = x + (size_t)n0 * HW;
        pv1 = v1 ? xb[off1] : 0.0f;
        pv2 = v2 ? xb[off2] : 0.0f;
        pv3 = v3 ? xb[off3] : 0.0f;
    }

    for (int k = 0; k < ZI; ++k) {
        const int n = n0 + k;
        // ---- phase Z: commit prefetched tile to xin; zero hist ----
        xin[i1] = pv1;
        xin[i2] = pv2;
        if (tid == 0) xin[1024] = pv3;
        {
            float4* h4 = (float4*)hist;               // 8972 = 2243*4
            for (int i = tid; i < HISTF / 4; i += BD)
                h4[i] = make_float4(0.f, 0.f, 0.f, 0.f);
        }
        __syncthreads();

        // ---- phase S: Sobel + phase + 2-bin scatter (pure stores, R11-proven) ----
        for (int p = tid; p < HR * HC; p += BD) {
            int hr = p / HC, hc = p - (p / HC) * HC;
            int hy = oy0 - 1 + hr, hx = ox0 - 1 + hc;
            if ((unsigned)hy >= H || (unsigned)hx >= W) continue;  // pool pad: zero
            const float* xr = &xin[hr * IC + hc];
            float a00 = xr[0],      a01 = xr[1],          a02 = xr[2];
            float a10 = xr[IC],                           a12 = xr[IC + 2];
            float a20 = xr[2 * IC], a21 = xr[2 * IC + 1], a22 = xr[2 * IC + 2];

            // exact numpy-order f32 conv (no contraction) — proven in round 3
            float gxv = __fadd_rn(a00, -a02);
            gxv = __fadd_rn(gxv, __fmul_rn(2.0f, a10));
            gxv = __fadd_rn(gxv, -__fmul_rn(2.0f, a12));
            gxv = __fadd_rn(gxv, a20);
            gxv = __fadd_rn(gxv, -a22);
            float gyv = __fadd_rn(a00, __fmul_rn(2.0f, a01));
            gyv = __fadd_rn(gyv, a02);
            gyv = __fadd_rn(gyv, -a20);
            gyv = __fadd_rn(gyv, -__fmul_rn(2.0f, a21));
            gyv = __fadd_rn(gyv, -a22);

            float ay_ = fabsf(gxv), ax_ = fabsf(gyv);
            float hi = fmaxf(ax_, ay_), lo = fminf(ax_, ay_);
            if (hi == 0.0f) continue;            // atan2(0,0)=0 -> contributes 0
            float nrm = __builtin_amdgcn_sqrtf(
                __fadd_rn(__fmul_rn(gxv, gxv), __fmul_rn(gyv, gyv)));

            // fast f32 atan2(gxv, gyv) * 10/pi, divide-free
            bool exact = (hi < 1e-30f) || (hi > 1e30f);
            float pint = 0.0f;
            if (!exact) {
                float t  = lo * __builtin_amdgcn_rcpf(hi);
                bool red = t > 0.41421356f;
                float u  = red ? (t - 1.0f) * __builtin_amdgcn_rcpf(t + 1.0f) : t;
                float z  = u * u;
                float pl = ((8.05374449538e-2f * z - 1.38776856032e-1f) * z
                            + 1.99777106478e-1f) * z - 3.33329491539e-1f;
                float a  = fmaf(u * z, pl, u);
                if (red) a += 0.78539816339744831f;
                if (ay_ > ax_) a = 1.57079632679489662f - a;
                if (gyv < 0.0f) a = 3.14159265358979324f - a;
                float ph = (gxv < 0.0f) ? -a : a;
                pint = ph * 3.18309886183790672f;
                if (fabsf(pint - rintf(pint)) < 1e-4f) exact = true;
            }

            float b_v, t_v;
            int ib, it;
            if (exact) {
                // bit-exact round-3 chain (matches np f32 reference)
                float phf = (float)atan2((double)gxv, (double)gyv);
                float pe  = __fmul_rn(__fdiv_rn(phf, (float)3.14159265358979323846), 10.0f);
                float bfv = floorf(pe), tfv = ceilf(pe);
                float fm = f32mod10(pe), bm = f32mod10(bfv), tm = f32mod10(tfv);
                t_v = __fmul_rn(nrm, __fsub_rn(1.0f, __fsub_rn(tm, fm)));
                b_v = __fmul_rn(nrm, __fsub_rn(1.0f, __fsub_rn(fm, bm)));
                ib = (((int)bfv % NB) + NB) % NB;
                it = (((int)tfv % NB) + NB) % NB;
            } else {
                // pint in (-10,10), >=1e-4 from any integer; wrap strips iff ib==9
                float bfv  = floorf(pint);
                float frac = pint - bfv;
                float fm   = (pint < 0.0f) ? pint + 10.0f : pint;
                b_v = nrm * (1.0f - frac);
                int bi = (int)bfv;
                ib = (bi < 0) ? bi + 10 : bi;
                if (ib == 9) { it = 0;      t_v = nrm * (1.0f + fm); }
                else         { it = ib + 1; t_v = nrm * frac; }
            }
            int cell = hr * HC + hc;
            if (ib == it) {
                hist[ib * HSTRIDE + cell] = __fadd_rn(b_v, t_v);
            } else {
                hist[ib * HSTRIDE + cell] = b_v;
                hist[it * HSTRIDE + cell] = t_v;
            }
        }
        __syncthreads();

        // ---- phase V: vertical sliding sum in place; colsum(0)->row 22;
        //      + issue next image's prefetch loads (hide under V+H) ----
        if (k + 1 < ZI) {
            const float* xb = x + (size_t)(n + 1) * HW;
            pv1 = v1 ? xb[off1] : 0.0f;
            pv2 = v2 ? xb[off2] : 0.0f;
            pv3 = v3 ? xb[off3] : 0.0f;
        }
        for (int q = tid; q < NB * HC; q += BD) {
            int b = q / HC, hc = q - (q / HC) * HC;
            float* col = &hist[b * HSTRIDE + hc];
            float s = 0.0f;
            #pragma unroll
            for (int hr = 0; hr < 8; ++hr) s += col[hr * HC];
            float s0 = s;                       // colsum(0) held in reg
            #pragma unroll 4
            for (int i = 1; i < TH; ++i) {
                s += col[(i + 7) * HC] - col[(i - 1) * HC];
                col[(i - 1) * HC] = s;          // row i-1 dead after this read
            }
            col[22 * HC] = s0;                  // row 22 dead after i=15 read
        }
        __syncthreads();

        // ---- phase H: horizontal sliding 8-sum, 8 outputs/unit ----
        float* __restrict__ outn = out + (size_t)n * (NB * OH * OW);
        for (int u = tid; u < NB * TH * 4; u += BD) {   // 640 units
            int b = u >> 6, i = (u >> 2) & 15, g8 = u & 3;
            const float* cs = &hist[b * HSTRIDE
                                    + (i == 0 ? 22 * HC : (i - 1) * HC) + 8 * g8];
            float p0 = cs[0], p1 = cs[1], p2 = cs[2],  p3 = cs[3];
            float p4 = cs[4], p5 = cs[5], p6 = cs[6],  p7 = cs[7];
            float p8 = cs[8], p9 = cs[9], p10 = cs[10], p11 = cs[11];
            float p12 = cs[12], p13 = cs[13], p14 = cs[14];
            float o0 = ((p0 + p1) + (p2 + p3)) + ((p4 + p5) + (p6 + p7));
            float o1 = o0 - p0 + p8;
            float o2 = o1 - p1 + p9;
            float o3 = o2 - p2 + p10;
            float o4 = o3 - p3 + p11;
            float o5 = o4 - p4 + p12;
            float o6 = o5 - p5 + p13;
            float o7 = o6 - p6 + p14;
            int oy = oy0 + i;
            if (oy < OH) {
                int oxg = ox0 + 8 * g8;
                float* po = outn + (size_t)(b * OH + oy) * OW + oxg;
                if (oxg + 7 < OW) {
                    po[0] = o0 * (1.0f / 64.0f); po[1] = o1 * (1.0f / 64.0f);
                    po[2] = o2 * (1.0f / 64.0f); po[3] = o3 * (1.0f / 64.0f);
                    po[4] = o4 * (1.0f / 64.0f); po[5] = o5 * (1.0f / 64.0f);
                    po[6] = o6 * (1.0f / 64.0f); po[7] = o7 * (1.0f / 64.0f);
                } else {
                    float ov[8] = {o0, o1, o2, o3, o4, o5, o6, o7};
                    #pragma unroll
                    for (int j = 0; j < 8; ++j)
                        if (oxg + j < OW) po[j] = ov[j] * (1.0f / 64.0f);
                }
            }
        }
        __syncthreads();   // hist/xin reuse safe for next iteration
    }
}

extern "C" void kernel_launch(void* const* d_in, const int* in_sizes, int n_in,
                              void* d_out, int out_size, void* d_ws, size_t ws_size,
                              hipStream_t stream) {
    const float* x = (const float*)d_in[0];
    // d_in[1] is the fixed Sobel weight [2,1,3,3]; hard-coded in the kernel.
    float* out = (float*)d_out;
    dim3 grid((OW + TW - 1) / TW, (OH + TH - 1) / TH, 32 / ZI);
    hog_fused<<<grid, dim3(BD), 0, stream>>>(x, out);
}

// Round 15
// 148.923 us; speedup vs baseline: 1.3710x; 1.3710x over previous
//
#include <hip/hip_runtime.h>
#include <math.h>

#define NB 10
#define H 512
#define W 512
#define HW (H * W)
#define OH 507
#define OW 507
#define TW 32           // output tile width
#define TH 16           // output tile height
#define HC 39           // hist cols
#define HR 23           // hist rows
#define IC 41           // xin cols
#define IR 25           // xin rows
#define BD 512          // 8 waves/block, 4 blocks/CU -> 32 waves/CU
#define HSTRIDE (HR * HC)        // 897
#define HISTF (NB * HSTRIDE + 2) // 8972 (pad -> clean float4 zero)
#define GX 16           // tiles in x
#define GY 32           // tiles in y
#define NIMG 32
#define NWG (GX * GY * NIMG)     // 16384, divisible by 8

// numpy float32 remainder (np.mod): fmod then sign-fix, each op exact IEEE f32.
__device__ __forceinline__ float f32mod10(float a) {
    float r = fmodf(a, 10.0f);
    if (r < 0.0f) r = __fadd_rn(r, 10.0f);
    return r;
}

__global__ __launch_bounds__(BD, 8)
void hog_fused(const float* __restrict__ x, float* __restrict__ out) {
    __shared__ __align__(16) float hist[HISTF];   // 8972 f
    __shared__ __align__(16) float xin[IR * IC];  // 1025 f  -> 39,988 B total

    // ---- XCD-aware bijective swizzle (T1): consecutive hardware blocks
    // (round-robin across 8 XCDs) -> contiguous tile chunks per XCD, so
    // adjacent-x tiles share an L2: halo fetches hit, output lines merge.
    const int orig = blockIdx.x;
    const int swz  = (orig & 7) * (NWG / 8) + (orig >> 3);
    const int tx   = swz & (GX - 1);
    const int ty   = (swz >> 4) & (GY - 1);
    const int n    = swz >> 9;

    const int tid = threadIdx.x;
    const int ox0 = tx * TW;
    const int oy0 = ty * TH;
    const float* __restrict__ xp = x + (size_t)n * HW;

    // ---- issue input loads FIRST (latency hides under hist zeroing) ----
    const int i1 = tid, i2 = tid + BD;
    int r1 = i1 / IC, c1 = i1 - r1 * IC;
    int r2 = i2 / IC, c2 = i2 - r2 * IC;
    int gy1 = oy0 - 2 + r1, gx1 = ox0 - 2 + c1;
    int gy2 = oy0 - 2 + r2, gx2 = ox0 - 2 + c2;
    const bool v1 = (unsigned)gy1 < H && (unsigned)gx1 < W;
    const bool v2 = (unsigned)gy2 < H && (unsigned)gx2 < W;
    float pv1 = v1 ? xp[gy1 * W + gx1] : 0.0f;
    float pv2 = v2 ? xp[gy2 * W + gx2] : 0.0f;
    float pv3 = 0.0f;
    if (tid == 0 && (unsigned)(oy0 + 22) < H && (unsigned)(ox0 + 38) < W)
        pv3 = xp[(oy0 + 22) * W + (ox0 + 38)];

    // ---- zero hist (independent of loads) ----
    {
        float4* h4 = (float4*)hist;               // 8972 = 2243*4
        for (int i = tid; i < HISTF / 4; i += BD)
            h4[i] = make_float4(0.f, 0.f, 0.f, 0.f);
    }
    // ---- commit tile to LDS ----
    xin[i1] = pv1;
    xin[i2] = pv2;
    if (tid == 0) xin[1024] = pv3;
    __syncthreads();

    // ---- phase S: Sobel + phase + 2-bin scatter (pure stores, R11-proven) ----
    for (int p = tid; p < HR * HC; p += BD) {
        int hr = p / HC, hc = p - (p / HC) * HC;
        int hy = oy0 - 1 + hr, hx = ox0 - 1 + hc;
        if ((unsigned)hy >= H || (unsigned)hx >= W) continue;  // pool pad: zero
        const float* xr = &xin[hr * IC + hc];
        float a00 = xr[0],      a01 = xr[1],          a02 = xr[2];
        float a10 = xr[IC],                           a12 = xr[IC + 2];
        float a20 = xr[2 * IC], a21 = xr[2 * IC + 1], a22 = xr[2 * IC + 2];

        // exact numpy-order f32 conv (no contraction) — proven in round 3
        float gxv = __fadd_rn(a00, -a02);
        gxv = __fadd_rn(gxv, __fmul_rn(2.0f, a10));
        gxv = __fadd_rn(gxv, -__fmul_rn(2.0f, a12));
        gxv = __fadd_rn(gxv, a20);
        gxv = __fadd_rn(gxv, -a22);
        float gyv = __fadd_rn(a00, __fmul_rn(2.0f, a01));
        gyv = __fadd_rn(gyv, a02);
        gyv = __fadd_rn(gyv, -a20);
        gyv = __fadd_rn(gyv, -__fmul_rn(2.0f, a21));
        gyv = __fadd_rn(gyv, -a22);

        float ay_ = fabsf(gxv), ax_ = fabsf(gyv);
        float hi = fmaxf(ax_, ay_), lo = fminf(ax_, ay_);
        if (hi == 0.0f) continue;            // atan2(0,0)=0 -> contributes 0
        float nrm = __builtin_amdgcn_sqrtf(
            __fadd_rn(__fmul_rn(gxv, gxv), __fmul_rn(gyv, gyv)));

        // fast f32 atan2(gxv, gyv) * 10/pi, divide-free
        bool exact = (hi < 1e-30f) || (hi > 1e30f);
        float pint = 0.0f;
        if (!exact) {
            float t  = lo * __builtin_amdgcn_rcpf(hi);
            bool red = t > 0.41421356f;
            float u  = red ? (t - 1.0f) * __builtin_amdgcn_rcpf(t + 1.0f) : t;
            float z  = u * u;
            float pl = ((8.05374449538e-2f * z - 1.38776856032e-1f) * z
                        + 1.99777106478e-1f) * z - 3.33329491539e-1f;
            float a  = fmaf(u * z, pl, u);
            if (red) a += 0.78539816339744831f;
            if (ay_ > ax_) a = 1.57079632679489662f - a;
            if (gyv < 0.0f) a = 3.14159265358979324f - a;
            float ph = (gxv < 0.0f) ? -a : a;
            pint = ph * 3.18309886183790672f;
            if (fabsf(pint - rintf(pint)) < 1e-4f) exact = true;
        }

        float b_v, t_v;
        int ib, it;
        if (exact) {
            // bit-exact round-3 chain (matches np f32 reference)
            float phf = (float)atan2((double)gxv, (double)gyv);
            float pe  = __fmul_rn(__fdiv_rn(phf, (float)3.14159265358979323846), 10.0f);
            float bfv = floorf(pe), tfv = ceilf(pe);
            float fm = f32mod10(pe), bm = f32mod10(bfv), tm = f32mod10(tfv);
            t_v = __fmul_rn(nrm, __fsub_rn(1.0f, __fsub_rn(tm, fm)));
            b_v = __fmul_rn(nrm, __fsub_rn(1.0f, __fsub_rn(fm, bm)));
            ib = (((int)bfv % NB) + NB) % NB;
            it = (((int)tfv % NB) + NB) % NB;
        } else {
            // pint in (-10,10), >=1e-4 from any integer; wrap strips iff ib==9
            float bfv  = floorf(pint);
            float frac = pint - bfv;
            float fm   = (pint < 0.0f) ? pint + 10.0f : pint;
            b_v = nrm * (1.0f - frac);
            int bi = (int)bfv;
            ib = (bi < 0) ? bi + 10 : bi;
            if (ib == 9) { it = 0;      t_v = nrm * (1.0f + fm); }
            else         { it = ib + 1; t_v = nrm * frac; }
        }
        int cell = hr * HC + hc;
        if (ib == it) {
            hist[ib * HSTRIDE + cell] = __fadd_rn(b_v, t_v);
        } else {
            hist[ib * HSTRIDE + cell] = b_v;
            hist[it * HSTRIDE + cell] = t_v;
        }
    }
    __syncthreads();

    // ---- phase V: vertical 8-row sliding sum, in place; colsum(0)->row 22 ----
    for (int q = tid; q < NB * HC; q += BD) {
        int b = q / HC, hc = q - (q / HC) * HC;
        float* col = &hist[b * HSTRIDE + hc];
        float s = 0.0f;
        #pragma unroll
        for (int hr = 0; hr < 8; ++hr) s += col[hr * HC];
        float s0 = s;                       // colsum(0) held in reg
        #pragma unroll 4
        for (int i = 1; i < TH; ++i) {
            s += col[(i + 7) * HC] - col[(i - 1) * HC];
            col[(i - 1) * HC] = s;          // row i-1 dead after this read
        }
        col[22 * HC] = s0;                  // row 22 dead after i=15 read
    }
    __syncthreads();

    // ---- phase H: horizontal sliding 8-sum, 8 outputs/unit ----
    float* __restrict__ outn = out + (size_t)n * (NB * OH * OW);
    for (int u = tid; u < NB * TH * 4; u += BD) {   // 640 units
        int b = u >> 6, i = (u >> 2) & 15, g8 = u & 3;
        const float* cs = &hist[b * HSTRIDE
                                + (i == 0 ? 22 * HC : (i - 1) * HC) + 8 * g8];
        float p0 = cs[0], p1 = cs[1], p2 = cs[2],  p3 = cs[3];
        float p4 = cs[4], p5 = cs[5], p6 = cs[6],  p7 = cs[7];
        float p8 = cs[8], p9 = cs[9], p10 = cs[10], p11 = cs[11];
        float p12 = cs[12], p13 = cs[13], p14 = cs[14];
        float o0 = ((p0 + p1) + (p2 + p3)) + ((p4 + p5) + (p6 + p7));
        float o1 = o0 - p0 + p8;
        float o2 = o1 - p1 + p9;
        float o3 = o2 - p2 + p10;
        float o4 = o3 - p3 + p11;
        float o5 = o4 - p4 + p12;
        float o6 = o5 - p5 + p13;
        float o7 = o6 - p6 + p14;
        int oy = oy0 + i;
        if (oy < OH) {
            int oxg = ox0 + 8 * g8;
            float* po = outn + (size_t)(b * OH + oy) * OW + oxg;
            if (oxg + 7 < OW) {
                po[0] = o0 * (1.0f / 64.0f); po[1] = o1 * (1.0f / 64.0f);
                po[2] = o2 * (1.0f / 64.0f); po[3] = o3 * (1.0f / 64.0f);
                po[4] = o4 * (1.0f / 64.0f); po[5] = o5 * (1.0f / 64.0f);
                po[6] = o6 * (1.0f / 64.0f); po[7] = o7 * (1.0f / 64.0f);
            } else {
                float ov[8] = {o0, o1, o2, o3, o4, o5, o6, o7};
                #pragma unroll
                for (int j = 0; j < 8; ++j)
                    if (oxg + j < OW) po[j] = ov[j] * (1.0f / 64.0f);
            }
        }
    }
}

extern "C" void kernel_launch(void* const* d_in, const int* in_sizes, int n_in,
                              void* d_out, int out_size, void* d_ws, size_t ws_size,
                              hipStream_t stream) {
    const float* x = (const float*)d_in[0];
    // d_in[1] is the fixed Sobel weight [2,1,3,3]; hard-coded in the kernel.
    float* out = (float*)d_out;
    hog_fused<<<dim3(NWG), dim3(BD), 0, stream>>>(x, out);
}